// Round 20
// baseline (176.917 us; speedup 1.0000x reference)
//
#include <hip/hip_runtime.h>
#include <math.h>

// B=8, N=1024, D=256, H=4, hd=64, k=153
// K1: f64 projections -> ws (32 MB); tgt also bf16 hi/lo FRAGMENT-MAJOR (4+4MB).
// K2a: split-bf16 MFMA adj GEMM (coalesced direct B) + transpose -> adj out:
//      int16 (adj*512) to ws+40MB if ws>=104MB (64MB), else f32 to out (128MB).
// K2b: pure select, 1 wave per row, SINGLE-PASS 1024-bucket select (key bits
//      31:22) + wide eps band re-ranked by exact f64 dot. r19 attribution:
//      k2b was 79.7us of 155.6 (2-pass radix serial chains); single pass
//      halves drains/broadcasts; (256,5) lifts occupancy 35%->~62%.
// Spill-free rule observed everywhere (r8/r10 lesson).

#define KSEL 153u
#define EPSX 140000u  // band half-width in keys; >= 2 * worst-case E (~63000)

typedef __attribute__((ext_vector_type(8))) short short8v;
typedef __attribute__((ext_vector_type(4))) float float4v;

__device__ __forceinline__ float gelu_f32(float x) {
    return 0.5f * x * (1.0f + erff(x * 0.70710678118654752f));
}

__device__ __forceinline__ unsigned long long d2key(double v) {
    unsigned long long u = (unsigned long long)__double_as_longlong(v);
    return (u >> 63) ? ~u : (u | 0x8000000000000000ull);
}

__device__ __forceinline__ unsigned lkeyf(float v) {
    float q = fmaf(v, 33554432.0f, 2147483648.0f);
    q = fminf(fmaxf(q, 0.0f), 4294967040.0f);
    return (unsigned)q;
}

__device__ __forceinline__ unsigned short b16(float x) {
    unsigned u = __float_as_uint(x);
    u += 0x7FFFu + ((u >> 16) & 1u);
    return (unsigned short)(u >> 16);
}
__device__ __forceinline__ float bf2f(unsigned short h) {
    return __uint_as_float(((unsigned)h) << 16);
}
__device__ __forceinline__ unsigned pk2(float a, float b) {
    return (unsigned)b16(a) | ((unsigned)b16(b) << 16);
}

#define LGKM0()                                             \
    do {                                                    \
        asm volatile("s_waitcnt lgkmcnt(0)" ::: "memory");  \
        __builtin_amdgcn_sched_barrier(0);                  \
    } while (0)

// ---------------- K1: projections, f64 accumulate; tgt also bf16 hi/lo ----------------
template <bool W32>
__global__ __launch_bounds__(256) void k1_proj(const float* __restrict__ x,
                                               const float* __restrict__ Wsrc,
                                               const float* __restrict__ Wtgt,
                                               double* __restrict__ ws,
                                               unsigned short* __restrict__ th,
                                               unsigned short* __restrict__ tl) {
    __shared__ float xs[32 * 68];
    __shared__ float wsh[32 * 68];
    const int t = threadIdx.x;
    const int bx = blockIdx.x;
    const int by = blockIdx.y;
    const int col0 = (by & 3) * 64;
    const float* __restrict__ W = (by < 4) ? Wsrc : Wtgt;
    double* __restrict__ outp = ws + ((by < 4) ? 0 : 2097152);

    double acc[4][4];
#pragma unroll
    for (int i = 0; i < 4; ++i)
#pragma unroll
        for (int j = 0; j < 4; ++j) acc[i][j] = 0.0;

    const int m_loc = (t & 15) * 4;
    const int c_loc = (t >> 4) * 4;

    for (int kt = 0; kt < 8; ++kt) {
        __syncthreads();
#pragma unroll
        for (int it = 0; it < 2; ++it) {
            int f4 = t + 256 * it;
            int m = f4 >> 3, k4 = f4 & 7;
            float4 v = *reinterpret_cast<const float4*>(&x[(bx * 64 + m) * 256 + kt * 32 + 4 * k4]);
            xs[(4 * k4 + 0) * 68 + m] = v.x;
            xs[(4 * k4 + 1) * 68 + m] = v.y;
            xs[(4 * k4 + 2) * 68 + m] = v.z;
            xs[(4 * k4 + 3) * 68 + m] = v.w;
        }
#pragma unroll
        for (int it = 0; it < 2; ++it) {
            int f4 = t + 256 * it;
            int k = f4 >> 4, c4 = f4 & 15;
            *reinterpret_cast<float4*>(&wsh[k * 68 + 4 * c4]) =
                *reinterpret_cast<const float4*>(&W[(kt * 32 + k) * 256 + col0 + 4 * c4]);
        }
        __syncthreads();
#pragma unroll
        for (int kk = 0; kk < 32; ++kk) {
            float4 a = *reinterpret_cast<const float4*>(&xs[kk * 68 + m_loc]);
            float4 b = *reinterpret_cast<const float4*>(&wsh[kk * 68 + c_loc]);
            double ad[4] = {a.x, a.y, a.z, a.w};
            double bd[4] = {b.x, b.y, b.z, b.w};
#pragma unroll
            for (int i = 0; i < 4; ++i)
#pragma unroll
                for (int j = 0; j < 4; ++j) acc[i][j] += ad[i] * bd[j];
        }
    }
    const int hd = by & 3;
#pragma unroll
    for (int i = 0; i < 4; ++i) {
        int m = bx * 64 + m_loc + i;
        int b = m >> 10, n = m & 1023;
        int bhd = b * 4 + hd;
        size_t base = ((size_t)(bhd * 1024 + n)) * 64 + c_loc;
        double2 v01, v23;
        v01.x = acc[i][0]; v01.y = acc[i][1];
        v23.x = acc[i][2]; v23.y = acc[i][3];
        *reinterpret_cast<double2*>(&outp[base]) = v01;
        *reinterpret_cast<double2*>(&outp[base + 2]) = v23;
        if (W32 && by >= 4) {
            float f0 = (float)acc[i][0], f1 = (float)acc[i][1];
            float f2 = (float)acc[i][2], f3 = (float)acc[i][3];
            unsigned short h0 = b16(f0), h1 = b16(f1), h2 = b16(f2), h3 = b16(f3);
            uint2 H, L;
            H.x = (unsigned)h0 | ((unsigned)h1 << 16);
            H.y = (unsigned)h2 | ((unsigned)h3 << 16);
            L.x = pk2(f0 - bf2f(h0), f1 - bf2f(h1));
            L.y = pk2(f2 - bf2f(h2), f3 - bf2f(h3));
            int T = n >> 4, colLow = n & 15;
            int ks = c_loc >> 5, kg = (c_loc >> 3) & 3, elem = c_loc & 7;
            size_t fidx = ((size_t)bhd * 65536) +
                          (size_t)(((T * 2 + ks) * 64 + kg * 16 + colLow) * 8 + elem);
            *reinterpret_cast<uint2*>(&th[fidx]) = H;
            *reinterpret_cast<uint2*>(&tl[fidx]) = L;
        }
    }
}

// ---------------- K2a: GEMM + transpose -> adj (int16 to adjS or f32 to out) ----------------
template <bool FAST, bool S16>
__global__ __launch_bounds__(256, 4) void k2a_gemm(const double* __restrict__ srcT,
                                                   const double* __restrict__ tgtT,
                                                   const unsigned short* __restrict__ th,
                                                   const unsigned short* __restrict__ tlo,
                                                   short* __restrict__ adjS,
                                                   float* __restrict__ out) {
    __shared__ __align__(16) float tr[16 * 512];  // 32KB; srcf overlaid at head

    unsigned short* sHI = reinterpret_cast<unsigned short*>(tr);
    unsigned short* sLO = sHI + 1024;

    const int t = threadIdx.x;
    const int lane = t & 63;
    const int wv = t >> 6;
    const int bid = (blockIdx.x & 7) * 256 + (blockIdx.x >> 3);
    const int bh = bid >> 6;
    const int itile = bid & 63;
    const int row0 = itile * 16;
    const int r0 = 4 * wv;
    const size_t tgtBase = (size_t)bh * 65536;
    const unsigned short* __restrict__ thb = th + tgtBase;
    const unsigned short* __restrict__ tlb = tlo + tgtBase;

    {
        int r = t >> 4, dq = (t & 15) * 4;
        const double* sp = &srcT[((size_t)bh * 1024 + row0 + r) * 64 + dq];
        double2 a = *reinterpret_cast<const double2*>(sp);
        double2 b = *reinterpret_cast<const double2*>(sp + 2);
        float f0 = (float)a.x, f1 = (float)a.y, f2 = (float)b.x, f3 = (float)b.y;
        unsigned short h0 = b16(f0), h1 = b16(f1), h2 = b16(f2), h3 = b16(f3);
        int s = dq >> 3;
        int idx = r * 64 + ((s ^ (r & 7)) << 3) + (dq & 7);
        uint2 H, L;
        H.x = (unsigned)h0 | ((unsigned)h1 << 16);
        H.y = (unsigned)h2 | ((unsigned)h3 << 16);
        L.x = pk2(f0 - bf2f(h0), f1 - bf2f(h1));
        L.y = pk2(f2 - bf2f(h2), f3 - bf2f(h3));
        *reinterpret_cast<uint2*>(&sHI[idx]) = H;
        *reinterpret_cast<uint2*>(&sLO[idx]) = L;
    }
    __syncthreads();

    short8v Ah[2], Al[2];
#pragma unroll
    for (int ks = 0; ks < 2; ++ks) {
        int idxA = (lane & 15) * 64 + (((4 * ks + (lane >> 4)) ^ (lane & 7)) << 3);
        Ah[ks] = *reinterpret_cast<const short8v*>(&sHI[idxA]);
        Al[ks] = *reinterpret_cast<const short8v*>(&sLO[idxA]);
    }

    const int colA = lane & 15;
    const int kgrp = lane >> 4;
    const size_t rowG0 = (size_t)bh * 1024 + row0 + r0;

#pragma unroll
    for (int h = 0; h < 2; ++h) {
        float4v acc[8];
#pragma unroll
        for (int a = 0; a < 8; ++a) acc[a] = (float4v){0.f, 0.f, 0.f, 0.f};

#pragma unroll
        for (int u = 0; u < 8; ++u) {
            const int T = 32 * h + 4 * u + wv;
#pragma unroll
            for (int ks = 0; ks < 2; ++ks) {
                short8v Bh, Bl;
                if (FAST) {
                    const size_t fbase = (size_t)(((T * 2 + ks) * 64 + lane) * 8);
                    Bh = *reinterpret_cast<const short8v*>(&thb[fbase]);
                    Bl = *reinterpret_cast<const short8v*>(&tlb[fbase]);
                } else {
                    const size_t cbase = (size_t)(16 * T + colA) * 64 + kgrp * 8;
                    const double* gp = &tgtT[tgtBase + cbase + 32 * ks];
                    double2 d0 = *reinterpret_cast<const double2*>(gp);
                    double2 d1 = *reinterpret_cast<const double2*>(gp + 2);
                    double2 d2 = *reinterpret_cast<const double2*>(gp + 4);
                    double2 d3 = *reinterpret_cast<const double2*>(gp + 6);
                    float f[8] = {(float)d0.x, (float)d0.y, (float)d1.x, (float)d1.y,
                                  (float)d2.x, (float)d2.y, (float)d3.x, (float)d3.y};
                    unsigned short hh[8];
#pragma unroll
                    for (int e = 0; e < 8; ++e) hh[e] = b16(f[e]);
                    unsigned Hw[4], Lw[4];
#pragma unroll
                    for (int e = 0; e < 4; ++e) {
                        Hw[e] = (unsigned)hh[2 * e] | ((unsigned)hh[2 * e + 1] << 16);
                        Lw[e] = pk2(f[2 * e] - bf2f(hh[2 * e]), f[2 * e + 1] - bf2f(hh[2 * e + 1]));
                    }
                    Bh = *reinterpret_cast<const short8v*>(Hw);
                    Bl = *reinterpret_cast<const short8v*>(Lw);
                }
                acc[u] = __builtin_amdgcn_mfma_f32_16x16x32_bf16(Ah[ks], Bh, acc[u], 0, 0, 0);
                acc[u] = __builtin_amdgcn_mfma_f32_16x16x32_bf16(Al[ks], Bh, acc[u], 0, 0, 0);
                acc[u] = __builtin_amdgcn_mfma_f32_16x16x32_bf16(Ah[ks], Bl, acc[u], 0, 0, 0);
            }
        }

        __syncthreads();  // h=0: srcf dead; h=1: half-0 reads done
#pragma unroll
        for (int u = 0; u < 8; ++u) {
            int colh = 16 * (4 * u + wv) + colA;
#pragma unroll
            for (int reg = 0; reg < 4; ++reg) {
                int row = 4 * kgrp + reg;
                tr[row * 512 + (colh ^ ((kgrp & 1) << 4))] = acc[u][reg];
            }
        }
        __syncthreads();
        const int rsw = (wv & 1) << 4;
#pragma unroll
        for (int ri = 0; ri < 4; ++ri) {
            int row = r0 + ri;
#pragma unroll
            for (int q = 0; q < 2; ++q) {
                int colh = 4 * lane + 256 * q;
                float4 v = *reinterpret_cast<const float4*>(&tr[row * 512 + (colh ^ rsw)]);
                if (S16) {
                    short4 s;
                    s.x = (short)__float2int_rn(fminf(fmaxf(v.x * 512.f, -32767.f), 32767.f));
                    s.y = (short)__float2int_rn(fminf(fmaxf(v.y * 512.f, -32767.f), 32767.f));
                    s.z = (short)__float2int_rn(fminf(fmaxf(v.z * 512.f, -32767.f), 32767.f));
                    s.w = (short)__float2int_rn(fminf(fmaxf(v.w * 512.f, -32767.f), 32767.f));
                    *reinterpret_cast<short4*>(&adjS[(rowG0 + ri) * 1024 + 512 * h + colh]) = s;
                } else {
                    *reinterpret_cast<float4*>(&out[(rowG0 + ri) * 1024 + 512 * h + colh]) = v;
                }
            }
        }
    }
}

// ---------------- K2b: single-pass 1024-bucket select (col = 16*lane+m) ----------------
template <bool S16>
__global__ __launch_bounds__(256, 5) void k2b_select(const double* __restrict__ srcT,
                                                     const double* __restrict__ tgtT,
                                                     const short* __restrict__ adjS,
                                                     float* __restrict__ out) {
    __shared__ __align__(16) unsigned hist[4][1024];  // 16KB, 4KB per wave

    const int t = threadIdx.x;
    const int lane = t & 63;
    const int wv = t >> 6;
    const int R = blockIdx.x * 4 + wv;  // 0..32767
    const int bh = R >> 10;
    const size_t tgtBase = (size_t)bh * 65536;
    const size_t base = (size_t)R * 1024;

    float vals[16];
    if (S16) {
#pragma unroll
        for (int q = 0; q < 2; ++q) {
            short8v s = *reinterpret_cast<const short8v*>(&adjS[base + 16 * lane + 8 * q]);
#pragma unroll
            for (int e = 0; e < 8; ++e) vals[8 * q + e] = (float)s[e] * (1.0f / 512.0f);
        }
    } else {
#pragma unroll
        for (int q = 0; q < 4; ++q) {
            float4 v = *reinterpret_cast<const float4*>(&out[base + 16 * lane + 4 * q]);
            vals[4 * q + 0] = v.x;
            vals[4 * q + 1] = v.y;
            vals[4 * q + 2] = v.z;
            vals[4 * q + 3] = v.w;
        }
    }

    unsigned* histw = hist[wv];
    unsigned ul[16];
#pragma unroll
    for (int m = 0; m < 16; ++m) ul[m] = lkeyf(vals[m]);

    // ---- single-pass 1024-bucket histogram (key bits 31:22) ----
#pragma unroll
    for (int e = 0; e < 4; ++e)
        *reinterpret_cast<uint4*>(&histw[16 * lane + 4 * e]) = make_uint4(0u, 0u, 0u, 0u);
    LGKM0();
#pragma unroll
    for (int m = 0; m < 16; ++m) atomicAdd(&histw[ul[m] >> 22], 1u);
    LGKM0();

    unsigned h[16];
#pragma unroll
    for (int e = 0; e < 4; ++e) {
        uint4 hv = *reinterpret_cast<const uint4*>(&histw[16 * lane + 4 * e]);
        h[4 * e + 0] = hv.x; h[4 * e + 1] = hv.y; h[4 * e + 2] = hv.z; h[4 * e + 3] = hv.w;
    }
    unsigned S = 0;
#pragma unroll
    for (int e = 0; e < 16; ++e) S += h[e];
    unsigned inc = S;  // suffix over lanes >= lane (higher lane = higher buckets)
#pragma unroll
    for (int off = 1; off < 64; off <<= 1) {
        unsigned o = __shfl_down(inc, off, 64);
        inc = (lane + off < 64) ? (inc + o) : inc;
    }
    unsigned above = inc - S;
    bool found = (above < KSEL) && (KSEL <= inc);
    unsigned long long bal = __ballot(found);
    int L = __ffsll(bal) - 1;
    // found lane walks its 16 buckets from the top
    int bq = 0;
    {
        unsigned cum = above;
#pragma unroll
        for (int q = 15; q >= 0; --q) {
            bool hit = (KSEL <= cum + h[q]);
            if (hit && bq == 0) bq = 16 * lane + q + 1;  // +1 to distinguish "unset"
            if (!hit) cum += h[q];
        }
    }
    const unsigned B = (unsigned)(__shfl(bq, L, 64) - 1);  // threshold bucket 0..1023

    const unsigned klo = (B << 22) - EPSX;
    const unsigned khi = ((B + 1) << 22) - 1u + EPSX;

    int ch = 0, cb = 0;
#pragma unroll
    for (int m = 0; m < 16; ++m) {
        ch += (ul[m] > khi) ? 1 : 0;
        cb += (ul[m] >= klo && ul[m] <= khi) ? 1 : 0;
    }
#pragma unroll
    for (int off = 32; off; off >>= 1) {
        ch += __shfl_xor(ch, off, 64);
        cb += __shfl_xor(cb, off, 64);
    }
    const unsigned need = KSEL - (unsigned)ch;
    const bool fastp = ((unsigned)cb == need);

    // candidate overlays on consumed histogram region
    unsigned long long* ckp = reinterpret_cast<unsigned long long*>(histw);  // [0..127]
    unsigned* cjp = histw + 128;                                             // [128..191]
    unsigned* ccp = histw + 192;

    unsigned long long selMask = 0ull;
    unsigned cidx[16];
    if (!fastp) {
        if (lane == 0) *ccp = 0u;
        LGKM0();
#pragma unroll
        for (int m = 0; m < 16; ++m) {
            cidx[m] = 0xFFFFFFFFu;
            if (ul[m] >= klo && ul[m] <= khi) {
                unsigned idx = atomicAdd(ccp, 1u);
                cidx[m] = idx;
                if (idx < 64u) cjp[idx] = (unsigned)(16 * lane + m);
            }
        }
        LGKM0();
        unsigned g = *ccp;
        if (g > 64u) g = 64u;
        if (lane < (int)g) {
            unsigned j = cjp[lane];
            const double2* sp = reinterpret_cast<const double2*>(&srcT[(size_t)R * 64]);
            const double2* tp = reinterpret_cast<const double2*>(&tgtT[tgtBase + (size_t)j * 64]);
            double a2 = 0.0;
#pragma unroll 8
            for (int d2 = 0; d2 < 32; ++d2) {
                double2 aa = sp[d2], bb = tp[d2];
                a2 = fma(aa.x, bb.x, fma(aa.y, bb.y, a2));
            }
            ckp[lane] = d2key(a2);
        }
        LGKM0();
        unsigned rnk2 = need;
        if (lane < (int)g) {
            unsigned long long myk = ckp[lane];
            unsigned myj = cjp[lane];
            rnk2 = 0;
            for (unsigned i = 0; i < g; ++i) {
                unsigned long long ki = ckp[i];
                rnk2 += (ki > myk || (ki == myk && cjp[i] < myj)) ? 1u : 0u;
            }
        }
        selMask = __ballot(lane < (int)g && rnk2 < need);
    }

#pragma unroll
    for (int q = 0; q < 4; ++q) {
        float4 o;
        float* op = &o.x;
#pragma unroll
        for (int e = 0; e < 4; ++e) {
            int m = 4 * q + e;
            bool sel;
            if (ul[m] > khi) sel = true;
            else if (ul[m] < klo) sel = false;
            else sel = fastp ? true
                             : ((cidx[m] < 64u) ? (((selMask >> cidx[m]) & 1ull) != 0ull) : false);
            float v = vals[m];
            op[e] = sel ? ((v > 3.0f) ? v : gelu_f32(v)) : 0.0f;
        }
        *reinterpret_cast<float4*>(&out[base + 16 * lane + 4 * q]) = o;
    }
}

extern "C" void kernel_launch(void* const* d_in, const int* in_sizes, int n_in,
                              void* d_out, int out_size, void* d_ws, size_t ws_size,
                              hipStream_t stream) {
    const float* x = (const float*)d_in[0];
    const float* Wsrc = (const float*)d_in[1];
    const float* Wtgt = (const float*)d_in[2];
    float* out = (float*)d_out;
    double* ws = (double*)d_ws;                                      // 32MB f64
    unsigned short* th = (unsigned short*)((char*)d_ws + 33554432);  // +4MB tgt hi (frag-major)
    unsigned short* tl = (unsigned short*)((char*)d_ws + 37748736);  // +4MB tgt lo (frag-major)
    short* adjS = (short*)((char*)d_ws + 41943040);                  // +64MB int16 adj (if room)

    const bool fast = (ws_size >= 40u * 1024u * 1024u);
    const bool s16 = (ws_size >= 104u * 1024u * 1024u);
    dim3 g1(128, 8);
    if (fast && s16) {
        k1_proj<true><<<g1, 256, 0, stream>>>(x, Wsrc, Wtgt, ws, th, tl);
        k2a_gemm<true, true><<<2048, 256, 0, stream>>>(ws, ws + 2097152, th, tl, adjS, out);
        k2b_select<true><<<8192, 256, 0, stream>>>(ws, ws + 2097152, adjS, out);
    } else if (fast) {
        k1_proj<true><<<g1, 256, 0, stream>>>(x, Wsrc, Wtgt, ws, th, tl);
        k2a_gemm<true, false><<<2048, 256, 0, stream>>>(ws, ws + 2097152, th, tl, adjS, out);
        k2b_select<false><<<8192, 256, 0, stream>>>(ws, ws + 2097152, adjS, out);
    } else {
        k1_proj<false><<<g1, 256, 0, stream>>>(x, Wsrc, Wtgt, ws, th, tl);
        k2a_gemm<false, false><<<2048, 256, 0, stream>>>(ws, ws + 2097152, th, tl, adjS, out);
        k2b_select<false><<<8192, 256, 0, stream>>>(ws, ws + 2097152, adjS, out);
    }
}

// Round 21
// 149.013 us; speedup vs baseline: 1.1873x; 1.1873x over previous
//
#include <hip/hip_runtime.h>
#include <math.h>

// B=8, N=1024, D=256, H=4, hd=64, k=153
// K1: f64 projections -> ws (32 MB); tgt also bf16 hi/lo FRAGMENT-MAJOR (4+4MB).
// K2a: split-bf16 MFMA adj GEMM (coalesced direct B) + transpose -> adj:
//      int16 (adj*512) to ws+40MB if ws>=104MB (64MB), else f32 to out (128MB).
// K2b: r19's PROVEN 2-pass radix select (bits 31:16) + narrow eps band +
//      rare f64-dot re-rank, at __launch_bounds__(256,6) for occupancy
//      (r19 ran (256,4) -> 35% occ; VGPR need 64 < cap ~85 -> no spill).
//      r20's single-pass 1024-bucket select REVERTED: wide bucket (2^22 keys)
//      made the f64 fallback fire on ~every row (FETCH 35->68MB, +20us).
// Spill-free rule observed everywhere (r8/r10 lesson).

#define KSEL 153u
#define EPSK 61000u   // f32-adj path: ~1.8e-3 * 2^25
#define EPSKS 76000u  // int16-adj path: (2^-10 + 9e-4) * 2^25 * margin

typedef __attribute__((ext_vector_type(8))) short short8v;
typedef __attribute__((ext_vector_type(4))) float float4v;

__device__ __forceinline__ float gelu_f32(float x) {
    return 0.5f * x * (1.0f + erff(x * 0.70710678118654752f));
}

__device__ __forceinline__ unsigned long long d2key(double v) {
    unsigned long long u = (unsigned long long)__double_as_longlong(v);
    return (u >> 63) ? ~u : (u | 0x8000000000000000ull);
}

__device__ __forceinline__ unsigned lkeyf(float v) {
    float q = fmaf(v, 33554432.0f, 2147483648.0f);
    q = fminf(fmaxf(q, 0.0f), 4294967040.0f);
    return (unsigned)q;
}

__device__ __forceinline__ unsigned short b16(float x) {
    unsigned u = __float_as_uint(x);
    u += 0x7FFFu + ((u >> 16) & 1u);
    return (unsigned short)(u >> 16);
}
__device__ __forceinline__ float bf2f(unsigned short h) {
    return __uint_as_float(((unsigned)h) << 16);
}
__device__ __forceinline__ unsigned pk2(float a, float b) {
    return (unsigned)b16(a) | ((unsigned)b16(b) << 16);
}

#define LGKM0()                                             \
    do {                                                    \
        asm volatile("s_waitcnt lgkmcnt(0)" ::: "memory");  \
        __builtin_amdgcn_sched_barrier(0);                  \
    } while (0)

// ---------------- K1: projections, f64 accumulate; tgt also bf16 hi/lo ----------------
template <bool W32>
__global__ __launch_bounds__(256) void k1_proj(const float* __restrict__ x,
                                               const float* __restrict__ Wsrc,
                                               const float* __restrict__ Wtgt,
                                               double* __restrict__ ws,
                                               unsigned short* __restrict__ th,
                                               unsigned short* __restrict__ tl) {
    __shared__ float xs[32 * 68];
    __shared__ float wsh[32 * 68];
    const int t = threadIdx.x;
    const int bx = blockIdx.x;
    const int by = blockIdx.y;
    const int col0 = (by & 3) * 64;
    const float* __restrict__ W = (by < 4) ? Wsrc : Wtgt;
    double* __restrict__ outp = ws + ((by < 4) ? 0 : 2097152);

    double acc[4][4];
#pragma unroll
    for (int i = 0; i < 4; ++i)
#pragma unroll
        for (int j = 0; j < 4; ++j) acc[i][j] = 0.0;

    const int m_loc = (t & 15) * 4;
    const int c_loc = (t >> 4) * 4;

    for (int kt = 0; kt < 8; ++kt) {
        __syncthreads();
#pragma unroll
        for (int it = 0; it < 2; ++it) {
            int f4 = t + 256 * it;
            int m = f4 >> 3, k4 = f4 & 7;
            float4 v = *reinterpret_cast<const float4*>(&x[(bx * 64 + m) * 256 + kt * 32 + 4 * k4]);
            xs[(4 * k4 + 0) * 68 + m] = v.x;
            xs[(4 * k4 + 1) * 68 + m] = v.y;
            xs[(4 * k4 + 2) * 68 + m] = v.z;
            xs[(4 * k4 + 3) * 68 + m] = v.w;
        }
#pragma unroll
        for (int it = 0; it < 2; ++it) {
            int f4 = t + 256 * it;
            int k = f4 >> 4, c4 = f4 & 15;
            *reinterpret_cast<float4*>(&wsh[k * 68 + 4 * c4]) =
                *reinterpret_cast<const float4*>(&W[(kt * 32 + k) * 256 + col0 + 4 * c4]);
        }
        __syncthreads();
#pragma unroll
        for (int kk = 0; kk < 32; ++kk) {
            float4 a = *reinterpret_cast<const float4*>(&xs[kk * 68 + m_loc]);
            float4 b = *reinterpret_cast<const float4*>(&wsh[kk * 68 + c_loc]);
            double ad[4] = {a.x, a.y, a.z, a.w};
            double bd[4] = {b.x, b.y, b.z, b.w};
#pragma unroll
            for (int i = 0; i < 4; ++i)
#pragma unroll
                for (int j = 0; j < 4; ++j) acc[i][j] += ad[i] * bd[j];
        }
    }
    const int hd = by & 3;
#pragma unroll
    for (int i = 0; i < 4; ++i) {
        int m = bx * 64 + m_loc + i;
        int b = m >> 10, n = m & 1023;
        int bhd = b * 4 + hd;
        size_t base = ((size_t)(bhd * 1024 + n)) * 64 + c_loc;
        double2 v01, v23;
        v01.x = acc[i][0]; v01.y = acc[i][1];
        v23.x = acc[i][2]; v23.y = acc[i][3];
        *reinterpret_cast<double2*>(&outp[base]) = v01;
        *reinterpret_cast<double2*>(&outp[base + 2]) = v23;
        if (W32 && by >= 4) {
            float f0 = (float)acc[i][0], f1 = (float)acc[i][1];
            float f2 = (float)acc[i][2], f3 = (float)acc[i][3];
            unsigned short h0 = b16(f0), h1 = b16(f1), h2 = b16(f2), h3 = b16(f3);
            uint2 H, L;
            H.x = (unsigned)h0 | ((unsigned)h1 << 16);
            H.y = (unsigned)h2 | ((unsigned)h3 << 16);
            L.x = pk2(f0 - bf2f(h0), f1 - bf2f(h1));
            L.y = pk2(f2 - bf2f(h2), f3 - bf2f(h3));
            int T = n >> 4, colLow = n & 15;
            int ks = c_loc >> 5, kg = (c_loc >> 3) & 3, elem = c_loc & 7;
            size_t fidx = ((size_t)bhd * 65536) +
                          (size_t)(((T * 2 + ks) * 64 + kg * 16 + colLow) * 8 + elem);
            *reinterpret_cast<uint2*>(&th[fidx]) = H;
            *reinterpret_cast<uint2*>(&tl[fidx]) = L;
        }
    }
}

// ---------------- K2a: GEMM + transpose -> adj (int16 to adjS or f32 to out) ----------------
template <bool FAST, bool S16>
__global__ __launch_bounds__(256, 4) void k2a_gemm(const double* __restrict__ srcT,
                                                   const double* __restrict__ tgtT,
                                                   const unsigned short* __restrict__ th,
                                                   const unsigned short* __restrict__ tlo,
                                                   short* __restrict__ adjS,
                                                   float* __restrict__ out) {
    __shared__ __align__(16) float tr[16 * 512];  // 32KB; srcf overlaid at head

    unsigned short* sHI = reinterpret_cast<unsigned short*>(tr);
    unsigned short* sLO = sHI + 1024;

    const int t = threadIdx.x;
    const int lane = t & 63;
    const int wv = t >> 6;
    const int bid = (blockIdx.x & 7) * 256 + (blockIdx.x >> 3);
    const int bh = bid >> 6;
    const int itile = bid & 63;
    const int row0 = itile * 16;
    const int r0 = 4 * wv;
    const size_t tgtBase = (size_t)bh * 65536;
    const unsigned short* __restrict__ thb = th + tgtBase;
    const unsigned short* __restrict__ tlb = tlo + tgtBase;

    {
        int r = t >> 4, dq = (t & 15) * 4;
        const double* sp = &srcT[((size_t)bh * 1024 + row0 + r) * 64 + dq];
        double2 a = *reinterpret_cast<const double2*>(sp);
        double2 b = *reinterpret_cast<const double2*>(sp + 2);
        float f0 = (float)a.x, f1 = (float)a.y, f2 = (float)b.x, f3 = (float)b.y;
        unsigned short h0 = b16(f0), h1 = b16(f1), h2 = b16(f2), h3 = b16(f3);
        int s = dq >> 3;
        int idx = r * 64 + ((s ^ (r & 7)) << 3) + (dq & 7);
        uint2 H, L;
        H.x = (unsigned)h0 | ((unsigned)h1 << 16);
        H.y = (unsigned)h2 | ((unsigned)h3 << 16);
        L.x = pk2(f0 - bf2f(h0), f1 - bf2f(h1));
        L.y = pk2(f2 - bf2f(h2), f3 - bf2f(h3));
        *reinterpret_cast<uint2*>(&sHI[idx]) = H;
        *reinterpret_cast<uint2*>(&sLO[idx]) = L;
    }
    __syncthreads();

    short8v Ah[2], Al[2];
#pragma unroll
    for (int ks = 0; ks < 2; ++ks) {
        int idxA = (lane & 15) * 64 + (((4 * ks + (lane >> 4)) ^ (lane & 7)) << 3);
        Ah[ks] = *reinterpret_cast<const short8v*>(&sHI[idxA]);
        Al[ks] = *reinterpret_cast<const short8v*>(&sLO[idxA]);
    }

    const int colA = lane & 15;
    const int kgrp = lane >> 4;
    const size_t rowG0 = (size_t)bh * 1024 + row0 + r0;

#pragma unroll
    for (int h = 0; h < 2; ++h) {
        float4v acc[8];
#pragma unroll
        for (int a = 0; a < 8; ++a) acc[a] = (float4v){0.f, 0.f, 0.f, 0.f};

#pragma unroll
        for (int u = 0; u < 8; ++u) {
            const int T = 32 * h + 4 * u + wv;
#pragma unroll
            for (int ks = 0; ks < 2; ++ks) {
                short8v Bh, Bl;
                if (FAST) {
                    const size_t fbase = (size_t)(((T * 2 + ks) * 64 + lane) * 8);
                    Bh = *reinterpret_cast<const short8v*>(&thb[fbase]);
                    Bl = *reinterpret_cast<const short8v*>(&tlb[fbase]);
                } else {
                    const size_t cbase = (size_t)(16 * T + colA) * 64 + kgrp * 8;
                    const double* gp = &tgtT[tgtBase + cbase + 32 * ks];
                    double2 d0 = *reinterpret_cast<const double2*>(gp);
                    double2 d1 = *reinterpret_cast<const double2*>(gp + 2);
                    double2 d2 = *reinterpret_cast<const double2*>(gp + 4);
                    double2 d3 = *reinterpret_cast<const double2*>(gp + 6);
                    float f[8] = {(float)d0.x, (float)d0.y, (float)d1.x, (float)d1.y,
                                  (float)d2.x, (float)d2.y, (float)d3.x, (float)d3.y};
                    unsigned short hh[8];
#pragma unroll
                    for (int e = 0; e < 8; ++e) hh[e] = b16(f[e]);
                    unsigned Hw[4], Lw[4];
#pragma unroll
                    for (int e = 0; e < 4; ++e) {
                        Hw[e] = (unsigned)hh[2 * e] | ((unsigned)hh[2 * e + 1] << 16);
                        Lw[e] = pk2(f[2 * e] - bf2f(hh[2 * e]), f[2 * e + 1] - bf2f(hh[2 * e + 1]));
                    }
                    Bh = *reinterpret_cast<const short8v*>(Hw);
                    Bl = *reinterpret_cast<const short8v*>(Lw);
                }
                acc[u] = __builtin_amdgcn_mfma_f32_16x16x32_bf16(Ah[ks], Bh, acc[u], 0, 0, 0);
                acc[u] = __builtin_amdgcn_mfma_f32_16x16x32_bf16(Al[ks], Bh, acc[u], 0, 0, 0);
                acc[u] = __builtin_amdgcn_mfma_f32_16x16x32_bf16(Ah[ks], Bl, acc[u], 0, 0, 0);
            }
        }

        __syncthreads();  // h=0: srcf dead; h=1: half-0 reads done
#pragma unroll
        for (int u = 0; u < 8; ++u) {
            int colh = 16 * (4 * u + wv) + colA;
#pragma unroll
            for (int reg = 0; reg < 4; ++reg) {
                int row = 4 * kgrp + reg;
                tr[row * 512 + (colh ^ ((kgrp & 1) << 4))] = acc[u][reg];
            }
        }
        __syncthreads();
        const int rsw = (wv & 1) << 4;
#pragma unroll
        for (int ri = 0; ri < 4; ++ri) {
            int row = r0 + ri;
#pragma unroll
            for (int q = 0; q < 2; ++q) {
                int colh = 4 * lane + 256 * q;
                float4 v = *reinterpret_cast<const float4*>(&tr[row * 512 + (colh ^ rsw)]);
                if (S16) {
                    short4 s;
                    s.x = (short)__float2int_rn(fminf(fmaxf(v.x * 512.f, -32767.f), 32767.f));
                    s.y = (short)__float2int_rn(fminf(fmaxf(v.y * 512.f, -32767.f), 32767.f));
                    s.z = (short)__float2int_rn(fminf(fmaxf(v.z * 512.f, -32767.f), 32767.f));
                    s.w = (short)__float2int_rn(fminf(fmaxf(v.w * 512.f, -32767.f), 32767.f));
                    *reinterpret_cast<short4*>(&adjS[(rowG0 + ri) * 1024 + 512 * h + colh]) = s;
                } else {
                    *reinterpret_cast<float4*>(&out[(rowG0 + ri) * 1024 + 512 * h + colh]) = v;
                }
            }
        }
    }
}

// ---------------- K2b: pure per-wave select (r19 2-pass, occupancy 6) ----------------
template <bool S16>
__global__ __launch_bounds__(256, 6) void k2b_select(const double* __restrict__ srcT,
                                                     const double* __restrict__ tgtT,
                                                     const short* __restrict__ adjS,
                                                     float* __restrict__ out) {
    __shared__ __align__(16) unsigned hist[4][256];  // 4KB, per-wave

    const int t = threadIdx.x;
    const int lane = t & 63;
    const int wv = t >> 6;
    const int R = blockIdx.x * 4 + wv;  // 0..32767
    const int bh = R >> 10;
    const size_t tgtBase = (size_t)bh * 65536;
    const size_t base = (size_t)R * 1024;
    const unsigned eps = S16 ? EPSKS : EPSK;

    float vals[16];
    if (S16) {
#pragma unroll
        for (int q = 0; q < 2; ++q) {
            short8v s = *reinterpret_cast<const short8v*>(&adjS[base + 16 * lane + 8 * q]);
#pragma unroll
            for (int e = 0; e < 8; ++e) vals[8 * q + e] = (float)s[e] * (1.0f / 512.0f);
        }
    } else {
#pragma unroll
        for (int q = 0; q < 4; ++q) {
            float4 v = *reinterpret_cast<const float4*>(&out[base + 16 * lane + 4 * q]);
            vals[4 * q + 0] = v.x;
            vals[4 * q + 1] = v.y;
            vals[4 * q + 2] = v.z;
            vals[4 * q + 3] = v.w;
        }
    }

    unsigned* histw = hist[wv];
    unsigned* cjp = histw + 128;
    unsigned long long* ckp = reinterpret_cast<unsigned long long*>(histw);
    unsigned* ccp = histw + 192;

    unsigned ul[16];
#pragma unroll
    for (int m = 0; m < 16; ++m) ul[m] = lkeyf(vals[m]);

    // 2-pass radix on top 16 bits
    unsigned prefA = 0u, maskA = 0u, rk = KSEL;
#pragma unroll 1
    for (int p = 1; p >= 0; --p) {
        const int sh = 16 + 8 * p;
        *reinterpret_cast<uint4*>(&histw[4 * lane]) = make_uint4(0u, 0u, 0u, 0u);
        LGKM0();
#pragma unroll
        for (int m = 0; m < 16; ++m) {
            if ((ul[m] & maskA) == prefA)
                atomicAdd(&histw[(ul[m] >> sh) & 255u], 1u);
        }
        LGKM0();
        unsigned h0 = histw[4 * lane + 0], h1 = histw[4 * lane + 1];
        unsigned h2 = histw[4 * lane + 2], h3 = histw[4 * lane + 3];
        unsigned S = h0 + h1 + h2 + h3;
        unsigned inc = S;
#pragma unroll
        for (int off = 1; off < 64; off <<= 1) {
            unsigned o = __shfl_down(inc, off, 64);
            inc = (lane + off < 64) ? (inc + o) : inc;
        }
        unsigned above = inc - S;
        bool found = (above < rk) && (rk <= inc);
        unsigned long long bal = __ballot(found);
        int L = __ffsll(bal) - 1;
        unsigned hh[4];
        hh[0] = __shfl(h0, L, 64);
        hh[1] = __shfl(h1, L, 64);
        hh[2] = __shfl(h2, L, 64);
        hh[3] = __shfl(h3, L, 64);
        unsigned cum = __shfl(above, L, 64);
        int bsel = -1;
#pragma unroll
        for (int q = 3; q >= 0; --q) {
            if (bsel < 0) {
                if (rk <= cum + hh[q]) {
                    bsel = q;
                    rk = rk - cum;
                } else {
                    cum += hh[q];
                }
            }
        }
        prefA |= (unsigned)(4 * L + bsel) << sh;
        maskA |= 0xFFu << sh;
    }

    const unsigned klo = prefA - eps;
    const unsigned khi = prefA + 65535u + eps;

    int ch = 0, cb = 0;
#pragma unroll
    for (int m = 0; m < 16; ++m) {
        ch += (ul[m] > khi) ? 1 : 0;
        cb += (ul[m] >= klo && ul[m] <= khi) ? 1 : 0;
    }
#pragma unroll
    for (int off = 32; off; off >>= 1) {
        ch += __shfl_xor(ch, off, 64);
        cb += __shfl_xor(cb, off, 64);
    }
    const unsigned need = KSEL - (unsigned)ch;
    const bool fastp = ((unsigned)cb == need);

    unsigned long long selMask = 0ull;
    unsigned cidx[16];
    if (!fastp) {
        if (lane == 0) *ccp = 0u;
        LGKM0();
#pragma unroll
        for (int m = 0; m < 16; ++m) {
            cidx[m] = 0xFFFFFFFFu;
            if (ul[m] >= klo && ul[m] <= khi) {
                unsigned idx = atomicAdd(ccp, 1u);
                cidx[m] = idx;
                if (idx < 64u) cjp[idx] = (unsigned)(16 * lane + m);
            }
        }
        LGKM0();
        unsigned g = *ccp;
        if (g > 64u) g = 64u;
        if (lane < (int)g) {
            unsigned j = cjp[lane];
            const double2* sp = reinterpret_cast<const double2*>(&srcT[(size_t)R * 64]);
            const double2* tp = reinterpret_cast<const double2*>(&tgtT[tgtBase + (size_t)j * 64]);
            double a2 = 0.0;
#pragma unroll 8
            for (int d2 = 0; d2 < 32; ++d2) {
                double2 aa = sp[d2], bb = tp[d2];
                a2 = fma(aa.x, bb.x, fma(aa.y, bb.y, a2));
            }
            ckp[lane] = d2key(a2);
        }
        LGKM0();
        unsigned rnk2 = need;
        if (lane < (int)g) {
            unsigned long long myk = ckp[lane];
            unsigned myj = cjp[lane];
            rnk2 = 0;
            for (unsigned i = 0; i < g; ++i) {
                unsigned long long ki = ckp[i];
                rnk2 += (ki > myk || (ki == myk && cjp[i] < myj)) ? 1u : 0u;
            }
        }
        selMask = __ballot(lane < (int)g && rnk2 < need);
    }

#pragma unroll
    for (int q = 0; q < 4; ++q) {
        float4 o;
        float* op = &o.x;
#pragma unroll
        for (int e = 0; e < 4; ++e) {
            int m = 4 * q + e;
            bool sel;
            if (ul[m] > khi) sel = true;
            else if (ul[m] < klo) sel = false;
            else sel = fastp ? true
                             : ((cidx[m] < 64u) ? (((selMask >> cidx[m]) & 1ull) != 0ull) : false);
            float v = vals[m];
            op[e] = sel ? ((v > 3.0f) ? v : gelu_f32(v)) : 0.0f;
        }
        *reinterpret_cast<float4*>(&out[base + 16 * lane + 4 * q]) = o;
    }
}

extern "C" void kernel_launch(void* const* d_in, const int* in_sizes, int n_in,
                              void* d_out, int out_size, void* d_ws, size_t ws_size,
                              hipStream_t stream) {
    const float* x = (const float*)d_in[0];
    const float* Wsrc = (const float*)d_in[1];
    const float* Wtgt = (const float*)d_in[2];
    float* out = (float*)d_out;
    double* ws = (double*)d_ws;                                      // 32MB f64
    unsigned short* th = (unsigned short*)((char*)d_ws + 33554432);  // +4MB tgt hi (frag-major)
    unsigned short* tl = (unsigned short*)((char*)d_ws + 37748736);  // +4MB tgt lo (frag-major)
    short* adjS = (short*)((char*)d_ws + 41943040);                  // +64MB int16 adj (if room)

    const bool fast = (ws_size >= 40u * 1024u * 1024u);
    const bool s16 = (ws_size >= 104u * 1024u * 1024u);
    dim3 g1(128, 8);
    if (fast && s16) {
        k1_proj<true><<<g1, 256, 0, stream>>>(x, Wsrc, Wtgt, ws, th, tl);
        k2a_gemm<true, true><<<2048, 256, 0, stream>>>(ws, ws + 2097152, th, tl, adjS, out);
        k2b_select<true><<<8192, 256, 0, stream>>>(ws, ws + 2097152, adjS, out);
    } else if (fast) {
        k1_proj<true><<<g1, 256, 0, stream>>>(x, Wsrc, Wtgt, ws, th, tl);
        k2a_gemm<true, false><<<2048, 256, 0, stream>>>(ws, ws + 2097152, th, tl, adjS, out);
        k2b_select<false><<<8192, 256, 0, stream>>>(ws, ws + 2097152, adjS, out);
    } else {
        k1_proj<false><<<g1, 256, 0, stream>>>(x, Wsrc, Wtgt, ws, th, tl);
        k2a_gemm<false, false><<<2048, 256, 0, stream>>>(ws, ws + 2097152, th, tl, adjS, out);
        k2b_select<false><<<8192, 256, 0, stream>>>(ws, ws + 2097152, adjS, out);
    }
}